// Round 1
// baseline (326.276 us; speedup 1.0000x reference)
//
#include <hip/hip_runtime.h>

typedef _Float16 f16x8 __attribute__((ext_vector_type(8)));
typedef float f32x4 __attribute__((ext_vector_type(4)));

#define MFMA_F16(a, b, c) __builtin_amdgcn_mfma_f32_16x16x32_f16((a), (b), (c), 0, 0, 0)
#define STRH 136   // h_tile row stride in halves

__device__ __forceinline__ unsigned int pkrtz(float a, float b) {
    return __builtin_bit_cast(unsigned int, __builtin_amdgcn_cvt_pkrtz(a, b));
}

#define GLDS(g, l) __builtin_amdgcn_global_load_lds(                      \
    (const __attribute__((address_space(1))) void*)(g),                   \
    (__attribute__((address_space(3))) void*)(l), 16, 0, 0)

// ws byte layout:
//   [0, 40960)       c2 frags fp16 [s=40][lane=64][j=8]
//                    slot s: rr=s/10, g=s%10; lane l: n=l&15 (out ch), q=l>>4;
//                    element = c2[n][i][g] with i=(rr*4+q)*8+j
//                    (re-ordered vs old P=4s+q layout so the fused kernel can keep
//                     per-element u^{k^2} recurrence state across the 10 grid scales)
//   [40960, 41000)   bias2 fp32 [10]
//   [41472, 246272)  w1 fp16 frags [kt=25][T=8][lane=64][j=8] (n=T*16+(lane&15), k=kt*32+(lane>>4)*8+j)
__global__ __launch_bounds__(256) void prep_kernel(
    const float* __restrict__ coef, const float* __restrict__ wbias,
    const float* __restrict__ w2, const float* __restrict__ b2,
    const float* __restrict__ w1, float* __restrict__ ws)
{
    int idx = blockIdx.x * 256 + threadIdx.x;
    if (idx < 20480) {
        int l = (idx >> 3) & 63, j = idx & 7;
        int s = idx >> 9;                 // slot 0..39
        int n = l & 15, q = l >> 4;
        int rr = s / 10, g = s - rr * 10; // run 0..3, grid 0..9
        int i = ((rr * 4 + q) << 3) + j;  // 0..127
        float v = 0.f;
        if (n < 10) {
            float sum = 0.f;
            const float* cp = coef + i * 10 + g;   // coef[o*1280 + i*10 + g]
            const float* wp = w2 + n * 64;
            #pragma unroll 8
            for (int o = 0; o < 64; ++o)
                sum = fmaf(wp[o], cp[o * 1280], sum);
            v = 0.8673250706f * sum;    // RICKER_C folded in
        }
        _Float16 hv = (_Float16)v;
        ((unsigned short*)ws)[idx] = __builtin_bit_cast(unsigned short, hv);
    } else if (idx < 20490) {
        int n = idx - 20480;
        float sum = b2[n];
        for (int o = 0; o < 64; ++o)
            sum = fmaf(w2[n * 64 + o], wbias[o], sum);
        ws[10240 + n] = sum;
    } else if (idx >= 20736) {
        int t = idx - 20736;
        if (t < 102400) {
            int n = t / 800, k = t - n * 800;
            _Float16 hv = (_Float16)0.f;
            if (k < 784) hv = (_Float16)w1[n * 784 + k];
            int kt = k >> 5, ko = k & 31;
            int qq = ko >> 3, j = ko & 7;
            int T = n >> 4, ln = qq * 16 + (n & 15);
            int slot = ((kt * 8 + T) * 64 + ln) * 8 + j;
            ((unsigned short*)((char*)ws + 41472))[slot] =
                __builtin_bit_cast(unsigned short, hv);
        }
    }
}

// launch_bounds(256,2): 256-VGPR budget -> NO scratch spills (R3 spilled ~30
// dwords/thread at the (256,4)/64-VGPR allocation: WRITE_SIZE 30 MB vs 2.6 MB out).
__global__ __launch_bounds__(256, 2) void mnist_fused(
    const float* __restrict__ x, const float* __restrict__ b1,
    const float* __restrict__ ws, float* __restrict__ out)
{
    __shared__ __align__(16) unsigned short Bbuf[2][4096];      // 16384 B (dbuf w1 kt-tile)
    __shared__ __align__(16) unsigned short h_tile[64 * STRH];  // 17408 B -> 33.8 KB total

    const int tid  = threadIdx.x;
    const int lane = tid & 63;
    const int wv   = tid >> 6;         // wave = m-tile (16 rows)
    const int m    = lane & 15;
    const int q    = lane >> 4;
    const long row0 = (long)blockIdx.x * 64;

    const char* w1f = (const char*)ws + 41472;
    const float* pa = x + (row0 + wv * 16 + m) * 784 + q * 8;

    // ---- stage B tile kt=0 into Bbuf[0] (each wave: 2 KB via 2 async calls) ----
    {
        const char* g = w1f + wv * 2048 + lane * 16;
        char* l = (char*)&Bbuf[0][0] + wv * 2048;
        GLDS(g, l);
        GLDS(g + 1024, l + 1024);
    }

    f32x4 acc[8];
    #pragma unroll
    for (int T = 0; T < 8; ++T) acc[T] = (f32x4){0.f, 0.f, 0.f, 0.f};

    // ---- prefetch x for kt=0 ----
    float4 xc0 = *(const float4*)pa;
    float4 xc1 = *(const float4*)(pa + 4);

    // ================= phase 1: h = x @ w1^T + b1 (fp16 MFMA, LDS dbuf for B) ==========
    for (int kt = 0; kt < 25; ++kt) {
        __syncthreads();               // Bbuf[kt&1] staged; prev reads retired
        const int cur = kt & 1;
        if (kt < 24) {                 // async-stage next B tile (in flight thru MFMAs)
            const char* g = w1f + (kt + 1) * 8192 + wv * 2048 + lane * 16;
            char* l = (char*)&Bbuf[cur ^ 1][0] + wv * 2048;
            GLDS(g, l);
            GLDS(g + 1024, l + 1024);
        }
        float4 xn0 = xc0, xn1 = xc1;   // prefetch x for kt+1
        if (kt < 24) {
            int kn = (kt + 1) * 32;
            // kt+1==24, q>=2 -> k>=784: B frags are zero there, any finite A ok; clamp addr
            const float* p = (kn + q * 8 < 784) ? (pa + kn) : pa;
            xn0 = *(const float4*)p;
            xn1 = *(const float4*)(p + 4);
        }
        uint4 ap = make_uint4(pkrtz(xc0.x, xc0.y), pkrtz(xc0.z, xc0.w),
                              pkrtz(xc1.x, xc1.y), pkrtz(xc1.z, xc1.w));
        f16x8 A = __builtin_bit_cast(f16x8, ap);
        #pragma unroll
        for (int T = 0; T < 8; ++T) {
            uint4 braw = *(const uint4*)&Bbuf[cur][T * 512 + lane * 8];
            acc[T] = MFMA_F16(A, __builtin_bit_cast(f16x8, braw), acc[T]);
        }
        xc0 = xn0; xc1 = xn1;
    }

    // ---- epilogue: h_tile (fp16) = acc + b1 ;  C/D: col=lane&15, row=q*4+reg ----
    #pragma unroll
    for (int T = 0; T < 8; ++T) {
        float bias = b1[T * 16 + m];
        #pragma unroll
        for (int r = 0; r < 4; ++r) {
            _Float16 hv = (_Float16)(acc[T][r] + bias);
            h_tile[(wv * 16 + q * 4 + r) * STRH + T * 16 + m] =
                __builtin_bit_cast(unsigned short, hv);
        }
    }
    __syncthreads();

    // ================= phase 2: out = ricker(h*k) . coef2 (fp16 MFMA, c2 from L2) ======
    // psi(h*k) = C * (1 - z1*k^2) * u^{k^2},  z1 = h^2, u = exp(-z1/2).
    // Recurrence over k: a_{k+1} = a_k * b_k,  b_{k+1} = b_k * u^2  (a_1=u, b_1=u^3)
    // -> ONE exp per h element (32/lane) instead of one per psi value (320/lane),
    //    and 4 h_tile ds_read_b128 per lane instead of 40 (8-way bank-conflicted).
    f32x4 acc2 = (f32x4){0.f, 0.f, 0.f, 0.f};
    const unsigned short* hrow = h_tile + (wv * 16 + m) * STRH;
    const uint4* c2g = (const uint4*)ws;

    for (int rr = 0; rr < 4; ++rr) {
        const int iblk = rr * 4 + q;
        uint4 hraw = *(const uint4*)(hrow + iblk * 8);
        f16x8 hh = __builtin_bit_cast(f16x8, hraw);
        float z1[8], a[8], bb[8], u2[8];
        #pragma unroll
        for (int e = 0; e < 8; ++e) {
            float hf = (float)hh[e];
            z1[e] = hf * hf;
            float u = __expf(z1[e] * -0.5f);   // u = exp(-h^2/2)
            u2[e] = u * u;
            a[e]  = u;                         // u^{1}
            bb[e] = u * u2[e];                 // u^{3}
        }
        #pragma unroll
        for (int g = 0; g < 10; ++g) {
            const float kk = (float)((g + 1) * (g + 1));
            unsigned int pk[4];
            #pragma unroll
            for (int e = 0; e < 8; e += 2) {
                float t0 = z1[e]     * kk;
                float t1 = z1[e + 1] * kk;
                float p0 = __builtin_fmaf(-t0, a[e],     a[e]);      // (1 - z1 k^2) u^{k^2}
                float p1 = __builtin_fmaf(-t1, a[e + 1], a[e + 1]);
                pk[e >> 1] = pkrtz(p0, p1);
            }
            if (g < 9) {
                #pragma unroll
                for (int e = 0; e < 8; ++e) { a[e] *= bb[e]; bb[e] *= u2[e]; }
            }
            uint4 braw = c2g[(rr * 10 + g) * 64 + lane];
            acc2 = MFMA_F16(__builtin_bit_cast(f16x8, make_uint4(pk[0], pk[1], pk[2], pk[3])),
                            __builtin_bit_cast(f16x8, braw), acc2);
        }
    }

    // ---- store: C/D col = out-channel n, row = q*4+r within wave's 16-row tile ----
    if (m < 10) {
        float bias2 = ws[10240 + m];
        const long rb = row0 + wv * 16 + q * 4;
        #pragma unroll
        for (int r = 0; r < 4; ++r)
            out[(rb + r) * 10 + m] = acc2[r] + bias2;
    }
}

extern "C" void kernel_launch(void* const* d_in, const int* in_sizes, int n_in,
                              void* d_out, int out_size, void* d_ws, size_t ws_size,
                              hipStream_t stream) {
    const float* x     = (const float*)d_in[0];
    const float* w1    = (const float*)d_in[1];
    const float* b1    = (const float*)d_in[2];
    const float* coef  = (const float*)d_in[3];
    const float* wbias = (const float*)d_in[4];
    const float* w2    = (const float*)d_in[5];
    const float* b2    = (const float*)d_in[6];
    float* out = (float*)d_out;
    float* ws  = (float*)d_ws;

    const int Brows = in_sizes[0] / 784;   // 65536
    prep_kernel<<<481, 256, 0, stream>>>(coef, wbias, w2, b2, w1, ws);
    mnist_fused<<<Brows / 64, 256, 0, stream>>>(x, b1, ws, out);
}